// Round 3
// baseline (127.079 us; speedup 1.0000x reference)
//
#include <hip/hip_runtime.h>
#include <math.h>

#define BB   8
#define HH   384
#define WW   384
#define NN   96
#define HWSZ (HH * WW)
#define NSEG (NN - 1)
#define SEGF 12
#define SEGPAD 1152                  // NSEG*SEGF = 1140, padded
#define DMAXV 15.0f
#define ROWS_PER_BLK 12
#define NCHUNK (HH / ROWS_PER_BLK)   // 32
#define CROWS 12
#define CBANDS (HH / CROWS)          // 32
#define MAGICU 0x9E3779B9u

typedef unsigned long long u64;
typedef unsigned int u32;

// Relaxed agent-scope atomic store of a float pair (8B). Used ONLY for the
// tiny segs/partial handoffs (~40 KB total) -- cheap at this volume.
__device__ inline void st_pair(float* p, float lo, float hi)
{
    u64 v = ((u64)__float_as_uint(hi) << 32) | (u64)__float_as_uint(lo);
    __hip_atomic_store((u64*)p, v, __ATOMIC_RELAXED, __HIP_MEMORY_SCOPE_AGENT);
}

__device__ inline float ld_f32_coh(const float* p)
{
    u32 v = __hip_atomic_load((u32*)p, __ATOMIC_RELAXED, __HIP_MEMORY_SCOPE_AGENT);
    return __uint_as_float(v);
}

#define WAIT_ALL() asm volatile("s_waitcnt vmcnt(0) lgkmcnt(0)" ::: "memory")

// ---------------------------------------------------------------------------
// Separable 7x7 tap recovery (exact).
// ---------------------------------------------------------------------------
__device__ inline void load_taps(const float* __restrict__ fltr,
                                 float* __restrict__ sg, float* __restrict__ sdg)
{
    int tid = threadIdx.x;
    if (tid < 7) {
        float s = 0.f;
#pragma unroll
        for (int i = 0; i < 7; ++i) s += fabsf(fltr[i * 7 + tid]);
        sg[tid] = s;
    } else if (tid < 14) {
        int r = tid - 7;
        float s = 0.f;
#pragma unroll
        for (int j = 0; j < 7; ++j) s += fltr[r * 7 + j];
        sdg[r] = s;
    }
    __syncthreads();
}

// ---------------------------------------------------------------------------
// Kernel 1: fused separable conv. NORMAL write-back stores (full-line,
// full-BW; the dispatch boundary provides coherence to kernel 2 with one
// CP-driven flush instead of millions of write-through transactions).
// ---------------------------------------------------------------------------
__global__ __launch_bounds__(384) void conv_fused(
    const float* __restrict__ pred, const float* __restrict__ fltr,
    float2* __restrict__ g2, float2* __restrict__ gw2)
{
    __shared__ float sg[7], sdg[7];
    load_taps(fltr, sg, sdg);

    int blk = blockIdx.x;            // 256 blocks
    int b = blk & 7;                 // XCD co-location swizzle (perf only)
    int band = blk >> 3;
    int y0 = band * CROWS;
    int x = threadIdx.x;             // column 0..383
    const float* pb = pred + (size_t)b * HWSZ;
    bool xin = (x >= 3) && (x < WW - 3);

    float hg[7], hd[7], hga[7], hda[7];

#pragma unroll
    for (int q = 0; q < CROWS + 6; ++q) {
        float vg = 0.f, vd = 0.f, vga = 0.f, vda = 0.f;
        int r = y0 + q - 3;
        if (r >= 0 && r < HH) {
            const float* row = pb + r * WW;
            if (xin) {
#pragma unroll
                for (int k = 0; k < 7; ++k) {
                    float v  = row[x + k - 3];
                    float av = fabsf(v);
                    vg  = fmaf(v,  sg[k],  vg);
                    vd  = fmaf(v,  sdg[k], vd);
                    vga = fmaf(av, sg[k],  vga);
                    vda = fmaf(av, sdg[k], vda);
                }
            } else {
#pragma unroll
                for (int k = 0; k < 7; ++k) {
                    int ix = x + k - 3;
                    float v  = (ix >= 0 && ix < WW) ? row[ix] : 0.f;
                    float av = fabsf(v);
                    vg  = fmaf(v,  sg[k],  vg);
                    vd  = fmaf(v,  sdg[k], vd);
                    vga = fmaf(av, sg[k],  vga);
                    vda = fmaf(av, sdg[k], vda);
                }
            }
        }
        hg[q % 7] = vg; hd[q % 7] = vd; hga[q % 7] = vga; hda[q % 7] = vda;

        if (q >= 6) {
            int y = y0 + q - 6;
            float o0 = 0.f, o1 = 0.f, o2 = 0.f, o3 = 0.f;
#pragma unroll
            for (int j = 0; j < 7; ++j) {
                int s = (q - 6 + j) % 7;
                o0 = fmaf(hg[s],  sdg[j], o0);
                o1 = fmaf(hd[s],  sg[j],  o1);
                o2 = fmaf(hga[s], sdg[j], o2);
                o3 = fmaf(hda[s], sg[j],  o3);
            }
            size_t gi = (size_t)b * HWSZ + (size_t)y * WW + x;
            g2[gi]  = make_float2(o0 * 10.f, o1 * 10.f);
            gw2[gi] = make_float2(o2 * 10.f, o3 * 10.f);
        }
    }
}

// ---------------------------------------------------------------------------
// Bilinear sample on channel-interleaved 2-ch image; normal cached loads.
// ---------------------------------------------------------------------------
__device__ inline float2 bilin2i(const float2* __restrict__ img, float py, float px)
{
    float y = fminf(fmaxf(py, 0.0f), (float)(HH - 1));
    float x = fminf(fmaxf(px, 0.0f), (float)(WW - 1));
    int y0 = (int)floorf(y);
    int x0 = (int)floorf(x);
    int y1 = min(y0 + 1, HH - 1);
    bool xedge = (x0 + 1 > WW - 1);
    float wy = y - (float)y0;
    float wx = x - (float)x0;
    float4 r0 = *(const float4*)(img + y0 * WW + x0);
    float4 r1 = *(const float4*)(img + y1 * WW + x0);
    float2 v00 = make_float2(r0.x, r0.y);
    float2 v01 = xedge ? v00 : make_float2(r0.z, r0.w);
    float2 v10 = make_float2(r1.x, r1.y);
    float2 v11 = xedge ? v10 : make_float2(r1.z, r1.w);
    float w00 = (1.f - wy) * (1.f - wx);
    float w01 = (1.f - wy) * wx;
    float w10 = wy * (1.f - wx);
    float w11 = wy * wx;
    return make_float2(v00.x * w00 + v01.x * w01 + v10.x * w10 + v11.x * w11,
                       v00.y * w00 + v01.y * w01 + v10.y * w10 + v11.y * w11);
}

// write-through (coherent) seg record: 6 u64 relaxed atomic stores
__device__ inline void write_seg_wt(float* __restrict__ r,
                                    float py, float px, float qy, float qx, float wseg)
{
    float aby = qy - py, abx = qx - px;
    float denom = aby * aby + abx * abx + 1e-8f;
    float aab = py * aby + px * abx;
    float aa  = py * py + px * px;
    float reach = DMAXV + wseg;
    st_pair(r + 0,  py,  px);
    st_pair(r + 2,  aby, abx);
    st_pair(r + 4,  aab, denom);
    st_pair(r + 6,  1.0f / denom, aa);
    st_pair(r + 8,  wseg, fminf(py, qy) - reach);
    st_pair(r + 10, fmaxf(py, qy) + reach, 0.f);
}

// ---------------------------------------------------------------------------
// Kernel 2: snake (blocks 0..7, wave 0) -> segs handoff (37 KB write-through,
// ~1 us) -> render + reduction. g2/gw2 arrive coherent via dispatch boundary.
// Idempotent across graph replays (MAGIC-tagged deterministic data).
// ---------------------------------------------------------------------------
__global__ __launch_bounds__(384) void snake_render(
    const float* __restrict__ pred, const float* __restrict__ nodes,
    const float* __restrict__ widths,
    const float* __restrict__ g2f, const float* __restrict__ gw2f,
    float* __restrict__ segs, u64* __restrict__ pflag,
    u32* __restrict__ segflag, float* __restrict__ out)
{
    __shared__ float ss[NSEG * SEGF];
    __shared__ int slo, shi;
    __shared__ float swsum[6];

    int blk = blockIdx.x;            // 256 blocks
    int b   = blk & 7;               // image (XCD co-location, perf-only)
    int band = blk >> 3;             // render chunk
    int t = threadIdx.x;

    // prefetch this thread's 12 pred values (input array; always valid) so the
    // loads complete under the snake/spin wait
    int y0r = band * ROWS_PER_BLK;
    const float* pb = pred + (size_t)b * HWSZ + (size_t)y0r * WW + t;
    float pv[ROWS_PER_BLK];
#pragma unroll
    for (int ry = 0; ry < ROWS_PER_BLK; ++ry) pv[ry] = pb[ry * WW];

    if (t == 0) { slo = NSEG; shi = -1; }

    // ================= phase B: snake (blocks 0..7, wave 0) =================
    if (blk < 8 && t < 64) {
        const float2* gb  = (const float2*)g2f  + (size_t)b * HWSZ;
        const float2* gwb = (const float2*)gw2f + (size_t)b * HWSZ;
        const int HALF = NN / 2;       // 48
        bool act = (t < HALF);
        bool t0 = (t == 0), tl = (t == HALF - 1);

        float ay = 0.f, ax = 0.f, by = 0.f, bx = 0.f;
        if (act) {
            float4 n4 = *(const float4*)(nodes + (size_t)(b * NN + 2 * t) * 2);
            ay = n4.x; ax = n4.y; by = n4.z; bx = n4.w;
        }

        for (int s = 0; s < 50; ++s) {
            float2 fa = bilin2i(gb, ay, ax);
            float2 fb = bilin2i(gb, by, bx);

            float aLy = __shfl_up(ay, 1, 64),  aLx = __shfl_up(ax, 1, 64);
            float bLy = __shfl_up(by, 1, 64),  bLx = __shfl_up(bx, 1, 64);
            float aRy = __shfl_down(ay, 1, 64), aRx = __shfl_down(ax, 1, 64);
            float bRy = __shfl_down(by, 1, 64), bRx = __shfl_down(bx, 1, 64);
            bLy = t0 ? ay : bLy;  bLx = t0 ? ax : bLx;
            aRy = tl ? by : aRy;  aRx = tl ? bx : aRx;

            float d2m_y = aLy - 2.f * bLy + ay;
            float d2a_y = bLy - 2.f * ay + by;
            float d2b_y = ay  - 2.f * by + aRy;
            float d2p_y = by  - 2.f * aRy + bRy;
            d2m_y = t0 ? d2a_y : d2m_y;
            d2p_y = tl ? d2b_y : d2p_y;
            float d4a_y = d2m_y - 2.f * d2a_y + d2b_y;
            float d4b_y = d2a_y - 2.f * d2b_y + d2p_y;

            float d2m_x = aLx - 2.f * bLx + ax;
            float d2a_x = bLx - 2.f * ax + bx;
            float d2b_x = ax  - 2.f * bx + aRx;
            float d2p_x = bx  - 2.f * aRx + bRx;
            d2m_x = t0 ? d2a_x : d2m_x;
            d2p_x = tl ? d2b_x : d2p_x;
            float d4a_x = d2m_x - 2.f * d2a_x + d2b_x;
            float d4b_x = d2a_x - 2.f * d2b_x + d2p_x;

            ay += 0.1f * (0.01f * d2a_y - 0.01f * d4a_y + fa.x);
            ax += 0.1f * (0.01f * d2a_x - 0.01f * d4a_x + fa.y);
            by += 0.1f * (0.01f * d2b_y - 0.01f * d4b_y + fb.x);
            bx += 0.1f * (0.01f * d2b_x - 0.01f * d4b_x + fb.y);
        }

        {
            float bLy = __shfl_up(by, 1, 64), bLx = __shfl_up(bx, 1, 64);
            float aRy = __shfl_down(ay, 1, 64), aRx = __shfl_down(ax, 1, 64);
            float tay = 0.5f * (by - bLy), tax = 0.5f * (bx - bLx);
            if (t0) { tay = by - ay; tax = bx - ax; }
            float tby = 0.5f * (aRy - ay), tbx = 0.5f * (aRx - ax);
            if (tl) { tby = by - ay; tbx = bx - ax; }

            float na0 = -tax, na1 = tay;
            float nrm = sqrtf(na0 * na0 + na1 * na1) + 1e-6f;
            float nay = na0 / nrm, nax = na1 / nrm;
            float nb0 = -tbx, nb1 = tby;
            nrm = sqrtf(nb0 * nb0 + nb1 * nb1) + 1e-6f;
            float nby = nb0 / nrm, nbx = nb1 / nrm;

            float wa = 0.f, wb = 0.f;
            if (act) { wa = widths[b * NN + 2 * t]; wb = widths[b * NN + 2 * t + 1]; }
            for (int s = 0; s < 10; ++s) {
                float2 pa = bilin2i(gwb, ay + wa * nay, ax + wa * nax);
                float2 ma = bilin2i(gwb, ay - wa * nay, ax - wa * nax);
                float2 pb2 = bilin2i(gwb, by + wb * nby, bx + wb * nbx);
                float2 mb = bilin2i(gwb, by - wb * nby, bx - wb * nbx);
                float fa = 0.5f * ((pa.x * nay + pa.y * nax) - (ma.x * nay + ma.y * nax));
                float fb = 0.5f * ((pb2.x * nby + pb2.y * nbx) - (mb.x * nby + mb.y * nbx));
                wa = fmaxf(wa + 0.1f * fa, 0.5f);
                wb = fmaxf(wb + 0.1f * fb, 0.5f);
            }

            float aRy2 = __shfl_down(ay, 1, 64), aRx2 = __shfl_down(ax, 1, 64);
            float waR  = __shfl_down(wa, 1, 64);
            float* segb = segs + (size_t)b * SEGPAD;
            if (act) {
                write_seg_wt(segb + (size_t)(2 * t) * SEGF, ay, ax, by, bx,
                             0.5f * (wa + wb));
                if (t < HALF - 1)
                    write_seg_wt(segb + (size_t)(2 * t + 1) * SEGF, by, bx, aRy2, aRx2,
                                 0.5f * (wb + waR));
            }
        }
        WAIT_ALL();                  // seg stores committed at coherence point
        if (t == 0)
            __hip_atomic_store(&segflag[b], MAGICU,
                               __ATOMIC_RELAXED, __HIP_MEMORY_SCOPE_AGENT);
    } else if (blk >= 8 && t == 0) {
        while (__hip_atomic_load(&segflag[b],
                                 __ATOMIC_RELAXED, __HIP_MEMORY_SCOPE_AGENT) != MAGICU)
            __builtin_amdgcn_s_sleep(8);
        asm volatile("" ::: "memory");
    }

    __syncthreads();                 // segs ready; slo/shi initialized

    // ================= phase C: render 12 rows + partial sum =================
    {
        int y0 = y0r;
        const float* sb = segs + (size_t)b * SEGPAD;
        for (int j = t; j < NSEG * SEGF; j += 384)
            ss[j] = ld_f32_coh(sb + j);      // one-shot coherent staging
        __syncthreads();

        float cy0 = (float)y0, cy1 = (float)(y0 + ROWS_PER_BLK - 1);
        if (t < NSEG) {
            float ylo = ss[t * SEGF + 9];
            float yhi = ss[t * SEGF + 10];
            if (yhi >= cy0 && ylo <= cy1) {
                atomicMin(&slo, t);
                atomicMax(&shi, t);
            }
        }
        __syncthreads();
        int lo = slo, hi = shi;

        float px = (float)t;
        float px2 = px * px;
        float minv[ROWS_PER_BLK];
#pragma unroll
        for (int r = 0; r < ROWS_PER_BLK; ++r) minv[r] = DMAXV;

        for (int si = lo; si <= hi; ++si) {
            const float* r = ss + si * SEGF;
            float ax = r[1], abx = r[3], ws = r[8];
            float bxe = ax + abx;
            float reach = DMAXV + ws + 0.01f;
            if (px < fminf(ax, bxe) - reach || px > fmaxf(ax, bxe) + reach) continue;

            float ay = r[0], aby = r[2];
            float aab = r[4], denom = r[5], invd = r[6], aa = r[7];
            float dotpa_b = fmaf(px, abx, -aab);
            float pa2_b   = fmaf(px, -2.0f * ax, px2 + aa);
#pragma unroll
            for (int ry = 0; ry < ROWS_PER_BLK; ++ry) {
                float py = (float)(y0 + ry);
                float dotpa = fmaf(py, aby, dotpa_b);
                float tt = fminf(fmaxf(dotpa * invd, 0.0f), 1.0f);
                float pa2 = fmaf(py, fmaf(py, 1.0f, -2.0f * ay), pa2_b);
                float d2 = fmaf(tt, fmaf(tt, denom, -2.0f * dotpa), pa2);
                float d = sqrtf(fmaxf(d2, 0.0f));
                float v = fmaxf(d - ws, 0.0f);
                minv[ry] = fminf(minv[ry], v);
            }
        }

        float sq = 0.f;
#pragma unroll
        for (int ry = 0; ry < ROWS_PER_BLK; ++ry) {
            float diff = pv[ry] - minv[ry];
            sq = fmaf(diff, diff, sq);
        }

#pragma unroll
        for (int off = 32; off > 0; off >>= 1) sq += __shfl_down(sq, off, 64);
        if ((t & 63) == 0) swsum[t >> 6] = sq;
        __syncthreads();
        if (t == 0) {
            float tot = swsum[0] + swsum[1] + swsum[2] + swsum[3] + swsum[4] + swsum[5];
            u64 pvv = ((u64)MAGICU << 32) | (u64)__float_as_uint(tot);
            __hip_atomic_store(&pflag[blk], pvv,
                               __ATOMIC_RELAXED, __HIP_MEMORY_SCOPE_AGENT);
        }
    }

    // ================= final reduce: designated block 8 =================
    if (blk == 8) {
        __syncthreads();             // protect swsum reuse
        float v = 0.f;
        if (t < 256) {
            u64 pvv = __hip_atomic_load(&pflag[t], __ATOMIC_RELAXED,
                                        __HIP_MEMORY_SCOPE_AGENT);
            while ((u32)(pvv >> 32) != MAGICU) {
                __builtin_amdgcn_s_sleep(4);
                pvv = __hip_atomic_load(&pflag[t], __ATOMIC_RELAXED,
                                        __HIP_MEMORY_SCOPE_AGENT);
            }
            v = __uint_as_float((u32)pvv);
        }
#pragma unroll
        for (int off = 32; off > 0; off >>= 1) v += __shfl_down(v, off, 64);
        if ((t & 63) == 0) swsum[t >> 6] = v;
        __syncthreads();
        if (t == 0) {
            float tot = swsum[0] + swsum[1] + swsum[2] + swsum[3] + swsum[4] + swsum[5];
            out[0] = tot * (1.0f / (float)(BB * HWSZ));
        }
    }
}

extern "C" void kernel_launch(void* const* d_in, const int* in_sizes, int n_in,
                              void* d_out, int out_size, void* d_ws, size_t ws_size,
                              hipStream_t stream)
{
    const float* pred   = (const float*)d_in[0];   // (8,1,384,384)
    const float* nodes  = (const float*)d_in[1];   // (8,96,2)
    const float* widths = (const float*)d_in[2];   // (8,96)
    const float* fltr   = (const float*)d_in[3];   // (2,1,7,7)
    float* out = (float*)d_out;

    float* ws   = (float*)d_ws;
    float* g2   = ws;                               // 2*B*HW floats (float2 lanes)
    float* gw2  = g2 + (size_t)2 * BB * HWSZ;       // 2*B*HW
    float* segs = gw2 + (size_t)2 * BB * HWSZ;      // B * SEGPAD
    float* tail = segs + (size_t)BB * SEGPAD + 256; // pad away from segs
    u64* pflag = (u64*)tail;                        // 256 u64 (8B-aligned)
    u32* segflag = (u32*)(pflag + 256);             // 8
    // total ~19 MB << ws_size

    conv_fused<<<BB * CBANDS, 384, 0, stream>>>(pred, fltr,
                                                (float2*)g2, (float2*)gw2);
    snake_render<<<BB * NCHUNK, 384, 0, stream>>>(pred, nodes, widths, g2, gw2,
                                                  segs, pflag, segflag, out);
}

// Round 4
// 121.281 us; speedup vs baseline: 1.0478x; 1.0478x over previous
//
#include <hip/hip_runtime.h>
#include <math.h>

#define BB   8
#define HH   384
#define WW   384
#define NN   96
#define HWSZ (HH * WW)
#define NSEG (NN - 1)
#define SEGF 12
#define SEGPAD 1152                  // NSEG*SEGF = 1140, padded
#define DMAXV 15.0f
#define ROWS_PER_BLK 12
#define NCHUNK (HH / ROWS_PER_BLK)   // 32
#define CROWS 12
#define CBANDS (HH / CROWS)          // 32
#define MAGICU 0x9E3779B9u

typedef unsigned long long u64;
typedef unsigned int u32;

// Relaxed agent-scope atomic store of a float pair (8B). Used ONLY for the
// tiny segs handoff (~40 KB total) -- cheap at this volume.
__device__ inline void st_pair(float* p, float lo, float hi)
{
    u64 v = ((u64)__float_as_uint(hi) << 32) | (u64)__float_as_uint(lo);
    __hip_atomic_store((u64*)p, v, __ATOMIC_RELAXED, __HIP_MEMORY_SCOPE_AGENT);
}

__device__ inline float ld_f32_coh(const float* p)
{
    u32 v = __hip_atomic_load((u32*)p, __ATOMIC_RELAXED, __HIP_MEMORY_SCOPE_AGENT);
    return __uint_as_float(v);
}

#define WAIT_ALL() asm volatile("s_waitcnt vmcnt(0) lgkmcnt(0)" ::: "memory")

// ---------------------------------------------------------------------------
// Separable 7x7 tap recovery (exact).
// ---------------------------------------------------------------------------
__device__ inline void load_taps(const float* __restrict__ fltr,
                                 float* __restrict__ sg, float* __restrict__ sdg)
{
    int tid = threadIdx.x;
    if (tid < 7) {
        float s = 0.f;
#pragma unroll
        for (int i = 0; i < 7; ++i) s += fabsf(fltr[i * 7 + tid]);
        sg[tid] = s;
    } else if (tid < 14) {
        int r = tid - 7;
        float s = 0.f;
#pragma unroll
        for (int j = 0; j < 7; ++j) s += fltr[r * 7 + j];
        sdg[r] = s;
    }
    __syncthreads();
}

// ---------------------------------------------------------------------------
// Kernel 1: fused separable conv (unchanged; normal write-back stores,
// dispatch boundary provides coherence to kernel 2).
// ---------------------------------------------------------------------------
__global__ __launch_bounds__(384) void conv_fused(
    const float* __restrict__ pred, const float* __restrict__ fltr,
    float2* __restrict__ g2, float2* __restrict__ gw2)
{
    __shared__ float sg[7], sdg[7];
    load_taps(fltr, sg, sdg);

    int blk = blockIdx.x;            // 256 blocks
    int b = blk & 7;                 // XCD co-location swizzle (perf only)
    int band = blk >> 3;
    int y0 = band * CROWS;
    int x = threadIdx.x;             // column 0..383
    const float* pb = pred + (size_t)b * HWSZ;
    bool xin = (x >= 3) && (x < WW - 3);

    float hg[7], hd[7], hga[7], hda[7];

#pragma unroll
    for (int q = 0; q < CROWS + 6; ++q) {
        float vg = 0.f, vd = 0.f, vga = 0.f, vda = 0.f;
        int r = y0 + q - 3;
        if (r >= 0 && r < HH) {
            const float* row = pb + r * WW;
            if (xin) {
#pragma unroll
                for (int k = 0; k < 7; ++k) {
                    float v  = row[x + k - 3];
                    float av = fabsf(v);
                    vg  = fmaf(v,  sg[k],  vg);
                    vd  = fmaf(v,  sdg[k], vd);
                    vga = fmaf(av, sg[k],  vga);
                    vda = fmaf(av, sdg[k], vda);
                }
            } else {
#pragma unroll
                for (int k = 0; k < 7; ++k) {
                    int ix = x + k - 3;
                    float v  = (ix >= 0 && ix < WW) ? row[ix] : 0.f;
                    float av = fabsf(v);
                    vg  = fmaf(v,  sg[k],  vg);
                    vd  = fmaf(v,  sdg[k], vd);
                    vga = fmaf(av, sg[k],  vga);
                    vda = fmaf(av, sdg[k], vda);
                }
            }
        }
        hg[q % 7] = vg; hd[q % 7] = vd; hga[q % 7] = vga; hda[q % 7] = vda;

        if (q >= 6) {
            int y = y0 + q - 6;
            float o0 = 0.f, o1 = 0.f, o2 = 0.f, o3 = 0.f;
#pragma unroll
            for (int j = 0; j < 7; ++j) {
                int s = (q - 6 + j) % 7;
                o0 = fmaf(hg[s],  sdg[j], o0);
                o1 = fmaf(hd[s],  sg[j],  o1);
                o2 = fmaf(hga[s], sdg[j], o2);
                o3 = fmaf(hda[s], sg[j],  o3);
            }
            size_t gi = (size_t)b * HWSZ + (size_t)y * WW + x;
            g2[gi]  = make_float2(o0 * 10.f, o1 * 10.f);
            gw2[gi] = make_float2(o2 * 10.f, o3 * 10.f);
        }
    }
}

// ---------------------------------------------------------------------------
// Bilinear sample on channel-interleaved 2-ch image (ref-identical math).
// ---------------------------------------------------------------------------
__device__ inline float2 bilin2i(const float2* __restrict__ img, float py, float px)
{
    float y = fminf(fmaxf(py, 0.0f), (float)(HH - 1));
    float x = fminf(fmaxf(px, 0.0f), (float)(WW - 1));
    int y0 = (int)floorf(y);
    int x0 = (int)floorf(x);
    int y1 = min(y0 + 1, HH - 1);
    bool xedge = (x0 + 1 > WW - 1);
    float wy = y - (float)y0;
    float wx = x - (float)x0;
    float4 r0 = *(const float4*)(img + y0 * WW + x0);
    float4 r1 = *(const float4*)(img + y1 * WW + x0);
    float2 v00 = make_float2(r0.x, r0.y);
    float2 v01 = xedge ? v00 : make_float2(r0.z, r0.w);
    float2 v10 = make_float2(r1.x, r1.y);
    float2 v11 = xedge ? v10 : make_float2(r1.z, r1.w);
    float w00 = (1.f - wy) * (1.f - wx);
    float w01 = (1.f - wy) * wx;
    float w10 = wy * (1.f - wx);
    float w11 = wy * wx;
    return make_float2(v00.x * w00 + v01.x * w01 + v10.x * w10 + v11.x * w11,
                       v00.y * w00 + v01.y * w01 + v10.y * w10 + v11.y * w11);
}

// write-through (coherent) seg record: 6 u64 relaxed atomic stores
__device__ inline void write_seg_wt(float* __restrict__ r,
                                    float py, float px, float qy, float qx, float wseg)
{
    float aby = qy - py, abx = qx - px;
    float denom = aby * aby + abx * abx + 1e-8f;
    float aab = py * aby + px * abx;
    float aa  = py * py + px * px;
    float reach = DMAXV + wseg;
    st_pair(r + 0,  py,  px);
    st_pair(r + 2,  aby, abx);
    st_pair(r + 4,  aab, denom);
    st_pair(r + 6,  1.0f / denom, aa);
    st_pair(r + 8,  wseg, fminf(py, qy) - reach);
    st_pair(r + 10, fmaxf(py, qy) + reach, 0.f);
}

// ---------------------------------------------------------------------------
// Kernel 2: snake (blocks 0..7: 96 nodes, ONE node per lane, 2 balanced waves
// of 48 active lanes, LDS double-buffered neighbor exchange, 1 barrier/step;
// fext gathers issued before the exchange so latency hides under it)
// -> segs handoff (37 KB write-through) -> render + reduction.
// All FP expressions keep the exact shape/order of the verified kernel.
// ---------------------------------------------------------------------------
__global__ __launch_bounds__(384) void snake_render(
    const float* __restrict__ pred, const float* __restrict__ nodes,
    const float* __restrict__ widths,
    const float* __restrict__ g2f, const float* __restrict__ gw2f,
    float* __restrict__ segs, u64* __restrict__ pflag,
    u32* __restrict__ segflag, float* __restrict__ out)
{
    __shared__ float ss[NSEG * SEGF];
    __shared__ float2 posb[2][NN];    // double-buffered node positions
    __shared__ float  wbuf[NN];
    __shared__ int slo, shi;
    __shared__ float swsum[6];

    int blk = blockIdx.x;            // 256 blocks
    int b   = blk & 7;               // image (XCD co-location, perf-only)
    int band = blk >> 3;             // render chunk
    int t = threadIdx.x;

    // prefetch this thread's 12 pred values; loads complete under snake/spin
    int y0r = band * ROWS_PER_BLK;
    const float* pb = pred + (size_t)b * HWSZ + (size_t)y0r * WW + t;
    float pv[ROWS_PER_BLK];
#pragma unroll
    for (int ry = 0; ry < ROWS_PER_BLK; ++ry) pv[ry] = pb[ry * WW];

    if (t == 0) { slo = NSEG; shi = -1; }

    // ================= phase B: snake (blocks 0..7) =================
    if (blk < 8) {
        const float2* gb  = (const float2*)g2f  + (size_t)b * HWSZ;
        const float2* gwb = (const float2*)gw2f + (size_t)b * HWSZ;
        int wv = t >> 6, ln = t & 63;
        int n  = wv * 48 + ln;              // node index (balanced 48/48)
        bool act = (wv < 2) && (ln < 48);
        bool n0f = (n == 0), nlf = (n == NN - 1);

        float py = 0.f, px = 0.f;
        if (act) {
            float2 p0 = *(const float2*)(nodes + (size_t)(b * NN + n) * 2);
            py = p0.x; px = p0.y;
            posb[0][n] = p0;
        }
        __syncthreads();                    // barrier 1 (all 6 waves)

        // ---- 50 position steps: 1 barrier per step ----
        for (int s = 0; s < 50; ++s) {
            const float2* pcur = posb[s & 1];
            float2* pnxt = posb[(s & 1) ^ 1];
            if (act) {
                // issue fext gathers FIRST (depend only on updated pos)
                float yc = fminf(fmaxf(py, 0.0f), (float)(HH - 1));
                float xc = fminf(fmaxf(px, 0.0f), (float)(WW - 1));
                int y0i = (int)floorf(yc);
                int x0i = (int)floorf(xc);
                int y1i = min(y0i + 1, HH - 1);
                bool xedge = (x0i + 1 > WW - 1);
                float wy = yc - (float)y0i;
                float wx = xc - (float)x0i;
                float4 r0 = *(const float4*)(gb + y0i * WW + x0i);
                float4 r1 = *(const float4*)(gb + y1i * WW + x0i);

                // neighbor exchange via LDS (clamped idx == d2_open replication)
                float2 xm1 = pcur[max(n - 1, 0)];
                float2 xp1 = pcur[min(n + 1, NN - 1)];
                float2 xm2 = pcur[max(n - 2, 0)];
                float2 xp2 = pcur[min(n + 2, NN - 1)];

                // internal forces (identical FP expression shapes)
                float d2m_y = xm2.x - 2.f * xm1.x + py;
                float d2c_y = xm1.x - 2.f * py + xp1.x;
                float d2p_y = py - 2.f * xp1.x + xp2.x;
                float d2m_x = xm2.y - 2.f * xm1.y + px;
                float d2c_x = xm1.y - 2.f * px + xp1.y;
                float d2p_x = px - 2.f * xp1.y + xp2.y;
                d2m_y = n0f ? d2c_y : d2m_y;
                d2m_x = n0f ? d2c_x : d2m_x;
                d2p_y = nlf ? d2c_y : d2p_y;
                d2p_x = nlf ? d2c_x : d2p_x;
                float d4_y = d2m_y - 2.f * d2c_y + d2p_y;
                float d4_x = d2m_x - 2.f * d2c_x + d2p_x;

                // finish bilinear (loads have had the exchange to land)
                float2 v00 = make_float2(r0.x, r0.y);
                float2 v01 = xedge ? v00 : make_float2(r0.z, r0.w);
                float2 v10 = make_float2(r1.x, r1.y);
                float2 v11 = xedge ? v10 : make_float2(r1.z, r1.w);
                float w00 = (1.f - wy) * (1.f - wx);
                float w01 = (1.f - wy) * wx;
                float w10 = wy * (1.f - wx);
                float w11 = wy * wx;
                float fy = v00.x * w00 + v01.x * w01 + v10.x * w10 + v11.x * w11;
                float fx = v00.y * w00 + v01.y * w01 + v10.y * w10 + v11.y * w11;

                py += 0.1f * (0.01f * d2c_y - 0.01f * d4_y + fy);
                px += 0.1f * (0.01f * d2c_x - 0.01f * d4_x + fx);
                pnxt[n] = make_float2(py, px);
            }
            __syncthreads();                // barriers 2..51
        }
        // final positions are in posb[0] (50 even) and (py,px) registers

        // ---- tangent / normal / width loop (no cross-lane deps) ----
        float ny_ = 0.f, nx_ = 0.f, wn = 0.f;
        if (act) {
            float2 xm1 = posb[0][max(n - 1, 0)];
            float2 xp1 = posb[0][min(n + 1, NN - 1)];
            float ty, tx;
            if (n0f)      { ty = xp1.x - py;  tx = xp1.y - px; }
            else if (nlf) { ty = py - xm1.x;  tx = px - xm1.y; }
            else          { ty = 0.5f * (xp1.x - xm1.x); tx = 0.5f * (xp1.y - xm1.y); }

            float nn0 = -tx, nn1 = ty;
            float nrm = sqrtf(nn0 * nn0 + nn1 * nn1) + 1e-6f;
            ny_ = nn0 / nrm; nx_ = nn1 / nrm;

            wn = widths[b * NN + n];
            for (int s = 0; s < 10; ++s) {
                float2 gp = bilin2i(gwb, py + wn * ny_, px + wn * nx_);
                float2 gm = bilin2i(gwb, py - wn * ny_, px - wn * nx_);
                float fw = 0.5f * ((gp.x * ny_ + gp.y * nx_) - (gm.x * ny_ + gm.y * nx_));
                wn = fmaxf(wn + 0.1f * fw, 0.5f);
            }
            wbuf[n] = wn;
        }
        __syncthreads();                    // barrier 52: wbuf ready

        // ---- seg write: lane n -> seg n ----
        if (act && n < NSEG) {
            float2 q = posb[0][n + 1];
            float wq = wbuf[n + 1];
            write_seg_wt(segs + (size_t)b * SEGPAD + (size_t)n * SEGF,
                         py, px, q.x, q.y, 0.5f * (wn + wq));
        }
        WAIT_ALL();                         // this wave's seg stores committed
        __syncthreads();                    // barrier 53: all waves committed
        if (t == 0)
            __hip_atomic_store(&segflag[b], MAGICU,
                               __ATOMIC_RELAXED, __HIP_MEMORY_SCOPE_AGENT);
    } else {
        if (t == 0) {
            while (__hip_atomic_load(&segflag[b],
                                     __ATOMIC_RELAXED, __HIP_MEMORY_SCOPE_AGENT) != MAGICU)
                __builtin_amdgcn_s_sleep(8);
            asm volatile("" ::: "memory");
        }
    }

    __syncthreads();                 // segs ready; slo/shi initialized

    // ================= phase C: render 12 rows + partial sum =================
    {
        int y0 = y0r;
        const float* sb = segs + (size_t)b * SEGPAD;
        for (int j = t; j < NSEG * SEGF; j += 384)
            ss[j] = ld_f32_coh(sb + j);      // one-shot coherent staging
        __syncthreads();

        float cy0 = (float)y0, cy1 = (float)(y0 + ROWS_PER_BLK - 1);
        if (t < NSEG) {
            float ylo = ss[t * SEGF + 9];
            float yhi = ss[t * SEGF + 10];
            if (yhi >= cy0 && ylo <= cy1) {
                atomicMin(&slo, t);
                atomicMax(&shi, t);
            }
        }
        __syncthreads();
        int lo = slo, hi = shi;

        float px = (float)t;
        float px2 = px * px;
        float minv[ROWS_PER_BLK];
#pragma unroll
        for (int r = 0; r < ROWS_PER_BLK; ++r) minv[r] = DMAXV;

        for (int si = lo; si <= hi; ++si) {
            const float* r = ss + si * SEGF;
            float ax = r[1], abx = r[3], ws = r[8];
            float bxe = ax + abx;
            float reach = DMAXV + ws + 0.01f;
            if (px < fminf(ax, bxe) - reach || px > fmaxf(ax, bxe) + reach) continue;

            float ay = r[0], aby = r[2];
            float aab = r[4], denom = r[5], invd = r[6], aa = r[7];
            float dotpa_b = fmaf(px, abx, -aab);
            float pa2_b   = fmaf(px, -2.0f * ax, px2 + aa);
#pragma unroll
            for (int ry = 0; ry < ROWS_PER_BLK; ++ry) {
                float py = (float)(y0 + ry);
                float dotpa = fmaf(py, aby, dotpa_b);
                float tt = fminf(fmaxf(dotpa * invd, 0.0f), 1.0f);
                float pa2 = fmaf(py, fmaf(py, 1.0f, -2.0f * ay), pa2_b);
                float d2 = fmaf(tt, fmaf(tt, denom, -2.0f * dotpa), pa2);
                float d = sqrtf(fmaxf(d2, 0.0f));
                float v = fmaxf(d - ws, 0.0f);
                minv[ry] = fminf(minv[ry], v);
            }
        }

        float sq = 0.f;
#pragma unroll
        for (int ry = 0; ry < ROWS_PER_BLK; ++ry) {
            float diff = pv[ry] - minv[ry];
            sq = fmaf(diff, diff, sq);
        }

#pragma unroll
        for (int off = 32; off > 0; off >>= 1) sq += __shfl_down(sq, off, 64);
        if ((t & 63) == 0) swsum[t >> 6] = sq;
        __syncthreads();
        if (t == 0) {
            float tot = swsum[0] + swsum[1] + swsum[2] + swsum[3] + swsum[4] + swsum[5];
            u64 pvv = ((u64)MAGICU << 32) | (u64)__float_as_uint(tot);
            __hip_atomic_store(&pflag[blk], pvv,
                               __ATOMIC_RELAXED, __HIP_MEMORY_SCOPE_AGENT);
        }
    }

    // ================= final reduce: designated block 8 =================
    if (blk == 8) {
        __syncthreads();             // protect swsum reuse
        float v = 0.f;
        if (t < 256) {
            u64 pvv = __hip_atomic_load(&pflag[t], __ATOMIC_RELAXED,
                                        __HIP_MEMORY_SCOPE_AGENT);
            while ((u32)(pvv >> 32) != MAGICU) {
                __builtin_amdgcn_s_sleep(4);
                pvv = __hip_atomic_load(&pflag[t], __ATOMIC_RELAXED,
                                        __HIP_MEMORY_SCOPE_AGENT);
            }
            v = __uint_as_float((u32)pvv);
        }
#pragma unroll
        for (int off = 32; off > 0; off >>= 1) v += __shfl_down(v, off, 64);
        if ((t & 63) == 0) swsum[t >> 6] = v;
        __syncthreads();
        if (t == 0) {
            float tot = swsum[0] + swsum[1] + swsum[2] + swsum[3] + swsum[4] + swsum[5];
            out[0] = tot * (1.0f / (float)(BB * HWSZ));
        }
    }
}

extern "C" void kernel_launch(void* const* d_in, const int* in_sizes, int n_in,
                              void* d_out, int out_size, void* d_ws, size_t ws_size,
                              hipStream_t stream)
{
    const float* pred   = (const float*)d_in[0];   // (8,1,384,384)
    const float* nodes  = (const float*)d_in[1];   // (8,96,2)
    const float* widths = (const float*)d_in[2];   // (8,96)
    const float* fltr   = (const float*)d_in[3];   // (2,1,7,7)
    float* out = (float*)d_out;

    float* ws   = (float*)d_ws;
    float* g2   = ws;                               // 2*B*HW floats (float2 lanes)
    float* gw2  = g2 + (size_t)2 * BB * HWSZ;       // 2*B*HW
    float* segs = gw2 + (size_t)2 * BB * HWSZ;      // B * SEGPAD
    float* tail = segs + (size_t)BB * SEGPAD + 256; // pad away from segs
    u64* pflag = (u64*)tail;                        // 256 u64 (8B-aligned)
    u32* segflag = (u32*)(pflag + 256);             // 8
    // total ~19 MB << ws_size

    conv_fused<<<BB * CBANDS, 384, 0, stream>>>(pred, fltr,
                                                (float2*)g2, (float2*)gw2);
    snake_render<<<BB * NCHUNK, 384, 0, stream>>>(pred, nodes, widths, g2, gw2,
                                                  segs, pflag, segflag, out);
}

// Round 5
// 119.551 us; speedup vs baseline: 1.0630x; 1.0145x over previous
//
#include <hip/hip_runtime.h>
#include <math.h>

#define BB   8
#define HH   384
#define WW   384
#define NN   96
#define HWSZ (HH * WW)
#define NSEG (NN - 1)
#define SEGF 12
#define SEGPAD 1152                  // NSEG*SEGF = 1140, padded
#define DMAXV 15.0f
#define ROWS_PER_BLK 12
#define NCHUNK (HH / ROWS_PER_BLK)   // 32
#define CROWS 12
#define CBANDS (HH / CROWS)          // 32
#define MAGICU 0x9E3779B9u

typedef unsigned long long u64;
typedef unsigned int u32;

// ---------------------------------------------------------------------------
// Separable 7x7 tap recovery (exact).
// ---------------------------------------------------------------------------
__device__ inline void load_taps(const float* __restrict__ fltr,
                                 float* __restrict__ sg, float* __restrict__ sdg)
{
    int tid = threadIdx.x;
    if (tid < 7) {
        float s = 0.f;
#pragma unroll
        for (int i = 0; i < 7; ++i) s += fabsf(fltr[i * 7 + tid]);
        sg[tid] = s;
    } else if (tid < 14) {
        int r = tid - 7;
        float s = 0.f;
#pragma unroll
        for (int j = 0; j < 7; ++j) s += fltr[r * 7 + j];
        sdg[r] = s;
    }
    __syncthreads();
}

// ---------------------------------------------------------------------------
// Kernel 1: fused separable conv (unchanged; normal write-back stores,
// dispatch boundary provides coherence to kernel 2).
// ---------------------------------------------------------------------------
__global__ __launch_bounds__(384) void conv_fused(
    const float* __restrict__ pred, const float* __restrict__ fltr,
    float2* __restrict__ g2, float2* __restrict__ gw2)
{
    __shared__ float sg[7], sdg[7];
    load_taps(fltr, sg, sdg);

    int blk = blockIdx.x;            // 256 blocks
    int b = blk & 7;                 // XCD co-location swizzle (perf only)
    int band = blk >> 3;
    int y0 = band * CROWS;
    int x = threadIdx.x;             // column 0..383
    const float* pb = pred + (size_t)b * HWSZ;
    bool xin = (x >= 3) && (x < WW - 3);

    float hg[7], hd[7], hga[7], hda[7];

#pragma unroll
    for (int q = 0; q < CROWS + 6; ++q) {
        float vg = 0.f, vd = 0.f, vga = 0.f, vda = 0.f;
        int r = y0 + q - 3;
        if (r >= 0 && r < HH) {
            const float* row = pb + r * WW;
            if (xin) {
#pragma unroll
                for (int k = 0; k < 7; ++k) {
                    float v  = row[x + k - 3];
                    float av = fabsf(v);
                    vg  = fmaf(v,  sg[k],  vg);
                    vd  = fmaf(v,  sdg[k], vd);
                    vga = fmaf(av, sg[k],  vga);
                    vda = fmaf(av, sdg[k], vda);
                }
            } else {
#pragma unroll
                for (int k = 0; k < 7; ++k) {
                    int ix = x + k - 3;
                    float v  = (ix >= 0 && ix < WW) ? row[ix] : 0.f;
                    float av = fabsf(v);
                    vg  = fmaf(v,  sg[k],  vg);
                    vd  = fmaf(v,  sdg[k], vd);
                    vga = fmaf(av, sg[k],  vga);
                    vda = fmaf(av, sdg[k], vda);
                }
            }
        }
        hg[q % 7] = vg; hd[q % 7] = vd; hga[q % 7] = vga; hda[q % 7] = vda;

        if (q >= 6) {
            int y = y0 + q - 6;
            float o0 = 0.f, o1 = 0.f, o2 = 0.f, o3 = 0.f;
#pragma unroll
            for (int j = 0; j < 7; ++j) {
                int s = (q - 6 + j) % 7;
                o0 = fmaf(hg[s],  sdg[j], o0);
                o1 = fmaf(hd[s],  sg[j],  o1);
                o2 = fmaf(hga[s], sdg[j], o2);
                o3 = fmaf(hda[s], sg[j],  o3);
            }
            size_t gi = (size_t)b * HWSZ + (size_t)y * WW + x;
            g2[gi]  = make_float2(o0 * 10.f, o1 * 10.f);
            gw2[gi] = make_float2(o2 * 10.f, o3 * 10.f);
        }
    }
}

// ---------------------------------------------------------------------------
// Bilinear sample on channel-interleaved 2-ch image (ref-identical math).
// ---------------------------------------------------------------------------
__device__ inline float2 bilin2i(const float2* __restrict__ img, float py, float px)
{
    float y = fminf(fmaxf(py, 0.0f), (float)(HH - 1));
    float x = fminf(fmaxf(px, 0.0f), (float)(WW - 1));
    int y0 = (int)floorf(y);
    int x0 = (int)floorf(x);
    int y1 = min(y0 + 1, HH - 1);
    bool xedge = (x0 + 1 > WW - 1);
    float wy = y - (float)y0;
    float wx = x - (float)x0;
    float4 r0 = *(const float4*)(img + y0 * WW + x0);
    float4 r1 = *(const float4*)(img + y1 * WW + x0);
    float2 v00 = make_float2(r0.x, r0.y);
    float2 v01 = xedge ? v00 : make_float2(r0.z, r0.w);
    float2 v10 = make_float2(r1.x, r1.y);
    float2 v11 = xedge ? v10 : make_float2(r1.z, r1.w);
    float w00 = (1.f - wy) * (1.f - wx);
    float w01 = (1.f - wy) * wx;
    float w10 = wy * (1.f - wx);
    float w11 = wy * wx;
    return make_float2(v00.x * w00 + v01.x * w01 + v10.x * w10 + v11.x * w11,
                       v00.y * w00 + v01.y * w01 + v10.y * w10 + v11.y * w11);
}

// plain-store seg record (kernel boundary provides coherence to render)
__device__ inline void write_seg(float* __restrict__ r,
                                 float py, float px, float qy, float qx, float wseg)
{
    float aby = qy - py, abx = qx - px;
    float denom = aby * aby + abx * abx + 1e-8f;
    float aab = py * aby + px * abx;
    float aa  = py * py + px * px;
    float reach = DMAXV + wseg;
    r[0]  = py;   r[1]  = px;
    r[2]  = aby;  r[3]  = abx;
    r[4]  = aab;  r[5]  = denom;
    r[6]  = 1.0f / denom;
    r[7]  = aa;   r[8]  = wseg;
    r[9]  = fminf(py, qy) - reach;
    r[10] = fmaxf(py, qy) + reach;
    r[11] = 0.f;
}

// raw barrier with LDS-only drain: gathers stay in flight across it
__device__ inline void lds_barrier()
{
    asm volatile("s_waitcnt lgkmcnt(0)" ::: "memory");
    __builtin_amdgcn_sched_barrier(0);
    __builtin_amdgcn_s_barrier();
    __builtin_amdgcn_sched_barrier(0);
}

// ---------------------------------------------------------------------------
// Kernel 2: snake, 8 blocks x 128 threads (2 waves, 48 active lanes each,
// one node per lane). Software-pipelined: step s+1's bilinear gathers are
// ISSUED at the end of step s and cross a raw s_barrier (lgkmcnt drain only,
// NO vmcnt drain) -> load latency hides under the barrier + LDS exchange +
// d2/d4 of the next step. All FP expression shapes identical to verified.
// ---------------------------------------------------------------------------
__global__ __launch_bounds__(128) void snake_kernel(
    const float* __restrict__ nodes, const float* __restrict__ widths,
    const float* __restrict__ g2f, const float* __restrict__ gw2f,
    float* __restrict__ segs)
{
    __shared__ float2 posb[2][NN];    // double-buffered node positions
    __shared__ float  wbuf[NN];

    int b = blockIdx.x;               // image
    int t = threadIdx.x;
    int wv = t >> 6, ln = t & 63;
    int n  = wv * 48 + ln;            // node index (balanced 48/48)
    bool act = (ln < 48);
    bool n0f = (n == 0), nlf = (n == NN - 1);

    const float2* gb  = (const float2*)g2f  + (size_t)b * HWSZ;
    const float2* gwb = (const float2*)gw2f + (size_t)b * HWSZ;

    float py = 0.f, px = 0.f;
    float4 r0 = make_float4(0.f, 0.f, 0.f, 0.f), r1 = r0;
    float wy = 0.f, wx = 0.f;
    bool xedge = false;

    // prologue: load node, publish to LDS, issue gather for initial pos
    if (act) {
        float2 p0 = *(const float2*)(nodes + (size_t)(b * NN + n) * 2);
        py = p0.x; px = p0.y;
        posb[0][n] = p0;
        float yc = fminf(fmaxf(py, 0.0f), (float)(HH - 1));
        float xc = fminf(fmaxf(px, 0.0f), (float)(WW - 1));
        int y0i = (int)floorf(yc);
        int x0i = (int)floorf(xc);
        int y1i = min(y0i + 1, HH - 1);
        xedge = (x0i + 1 > WW - 1);
        wy = yc - (float)y0i;
        wx = xc - (float)x0i;
        r0 = *(const float4*)(gb + y0i * WW + x0i);
        r1 = *(const float4*)(gb + y1i * WW + x0i);
    }
    lds_barrier();

    // ---- 50 position steps, software-pipelined ----
    for (int s = 0; s < 50; ++s) {
        const float2* pcur = posb[s & 1];
        float2* pnxt = posb[(s & 1) ^ 1];
        if (act) {
            // LDS exchange + internal forces (overlaps in-flight gathers)
            float2 xm1 = pcur[max(n - 1, 0)];
            float2 xp1 = pcur[min(n + 1, NN - 1)];
            float2 xm2 = pcur[max(n - 2, 0)];
            float2 xp2 = pcur[min(n + 2, NN - 1)];

            float d2m_y = xm2.x - 2.f * xm1.x + py;
            float d2c_y = xm1.x - 2.f * py + xp1.x;
            float d2p_y = py - 2.f * xp1.x + xp2.x;
            float d2m_x = xm2.y - 2.f * xm1.y + px;
            float d2c_x = xm1.y - 2.f * px + xp1.y;
            float d2p_x = px - 2.f * xp1.y + xp2.y;
            d2m_y = n0f ? d2c_y : d2m_y;
            d2m_x = n0f ? d2c_x : d2m_x;
            d2p_y = nlf ? d2c_y : d2p_y;
            d2p_x = nlf ? d2c_x : d2p_x;
            float d4_y = d2m_y - 2.f * d2c_y + d2p_y;
            float d4_x = d2m_x - 2.f * d2c_x + d2p_x;

            // consume the gather issued LAST iteration (weights carried)
            float2 v00 = make_float2(r0.x, r0.y);
            float2 v01 = xedge ? v00 : make_float2(r0.z, r0.w);
            float2 v10 = make_float2(r1.x, r1.y);
            float2 v11 = xedge ? v10 : make_float2(r1.z, r1.w);
            float w00 = (1.f - wy) * (1.f - wx);
            float w01 = (1.f - wy) * wx;
            float w10 = wy * (1.f - wx);
            float w11 = wy * wx;
            float fy = v00.x * w00 + v01.x * w01 + v10.x * w10 + v11.x * w11;
            float fx = v00.y * w00 + v01.y * w01 + v10.y * w10 + v11.y * w11;

            py += 0.1f * (0.01f * d2c_y - 0.01f * d4_y + fy);
            px += 0.1f * (0.01f * d2c_x - 0.01f * d4_x + fx);

            // issue NEXT step's gather from the updated position
            float yc = fminf(fmaxf(py, 0.0f), (float)(HH - 1));
            float xc = fminf(fmaxf(px, 0.0f), (float)(WW - 1));
            int y0i = (int)floorf(yc);
            int x0i = (int)floorf(xc);
            int y1i = min(y0i + 1, HH - 1);
            xedge = (x0i + 1 > WW - 1);
            wy = yc - (float)y0i;
            wx = xc - (float)x0i;
            r0 = *(const float4*)(gb + y0i * WW + x0i);
            r1 = *(const float4*)(gb + y1i * WW + x0i);

            pnxt[n] = make_float2(py, px);
        }
        lds_barrier();                 // LDS drain only; gathers stay in flight
    }
    // final positions: posb[0][*] and (py,px) registers

    // ---- tangent / normal / width loop ----
    float ny_ = 0.f, nx_ = 0.f, wn = 0.f;
    if (act) {
        float2 xm1 = posb[0][max(n - 1, 0)];
        float2 xp1 = posb[0][min(n + 1, NN - 1)];
        float ty, tx;
        if (n0f)      { ty = xp1.x - py;  tx = xp1.y - px; }
        else if (nlf) { ty = py - xm1.x;  tx = px - xm1.y; }
        else          { ty = 0.5f * (xp1.x - xm1.x); tx = 0.5f * (xp1.y - xm1.y); }

        float nn0 = -tx, nn1 = ty;
        float nrm = sqrtf(nn0 * nn0 + nn1 * nn1) + 1e-6f;
        ny_ = nn0 / nrm; nx_ = nn1 / nrm;

        wn = widths[b * NN + n];
        for (int s = 0; s < 10; ++s) {
            float2 gp = bilin2i(gwb, py + wn * ny_, px + wn * nx_);
            float2 gm = bilin2i(gwb, py - wn * ny_, px - wn * nx_);
            float fw = 0.5f * ((gp.x * ny_ + gp.y * nx_) - (gm.x * ny_ + gm.y * nx_));
            wn = fmaxf(wn + 0.1f * fw, 0.5f);
        }
        wbuf[n] = wn;
    }
    __syncthreads();                   // wbuf ready (full drain fine here)

    // ---- seg write: plain stores; dispatch boundary -> render coherence ----
    if (act && n < NSEG) {
        float2 q = posb[0][n + 1];
        float wq = wbuf[n + 1];
        write_seg(segs + (size_t)b * SEGPAD + (size_t)n * SEGF,
                  py, px, q.x, q.y, 0.5f * (wn + wq));
    }
}

// ---------------------------------------------------------------------------
// Kernel 3: render 12 rows per block (256 blocks) + fused reduction via
// u64 MAGIC-tagged partials (idempotent across graph replays).
// ---------------------------------------------------------------------------
__global__ __launch_bounds__(384) void render_kernel(
    const float* __restrict__ pred, const float* __restrict__ segs,
    u64* __restrict__ pflag, float* __restrict__ out)
{
    __shared__ float ss[NSEG * SEGF];
    __shared__ int slo, shi;
    __shared__ float swsum[6];

    int blk = blockIdx.x;
    int b = blk & 7;                 // XCD co-location swizzle
    int band = blk >> 3;
    int y0 = band * ROWS_PER_BLK;
    int t = threadIdx.x;

    // prefetch this thread's 12 pred values
    const float* pb = pred + (size_t)b * HWSZ + (size_t)y0 * WW + t;
    float pv[ROWS_PER_BLK];
#pragma unroll
    for (int ry = 0; ry < ROWS_PER_BLK; ++ry) pv[ry] = pb[ry * WW];

    const float* sb = segs + (size_t)b * SEGPAD;
    for (int j = t; j < NSEG * SEGF; j += 384) ss[j] = sb[j];
    if (t == 0) { slo = NSEG; shi = -1; }
    __syncthreads();

    float cy0 = (float)y0, cy1 = (float)(y0 + ROWS_PER_BLK - 1);
    if (t < NSEG) {
        float ylo = ss[t * SEGF + 9];
        float yhi = ss[t * SEGF + 10];
        if (yhi >= cy0 && ylo <= cy1) {
            atomicMin(&slo, t);
            atomicMax(&shi, t);
        }
    }
    __syncthreads();
    int lo = slo, hi = shi;

    float px = (float)t;
    float px2 = px * px;
    float minv[ROWS_PER_BLK];
#pragma unroll
    for (int r = 0; r < ROWS_PER_BLK; ++r) minv[r] = DMAXV;

    for (int si = lo; si <= hi; ++si) {
        const float* r = ss + si * SEGF;
        float ax = r[1], abx = r[3], ws = r[8];
        float bxe = ax + abx;
        float reach = DMAXV + ws + 0.01f;
        if (px < fminf(ax, bxe) - reach || px > fmaxf(ax, bxe) + reach) continue;

        float ay = r[0], aby = r[2];
        float aab = r[4], denom = r[5], invd = r[6], aa = r[7];
        float dotpa_b = fmaf(px, abx, -aab);
        float pa2_b   = fmaf(px, -2.0f * ax, px2 + aa);
#pragma unroll
        for (int ry = 0; ry < ROWS_PER_BLK; ++ry) {
            float py = (float)(y0 + ry);
            float dotpa = fmaf(py, aby, dotpa_b);
            float tt = fminf(fmaxf(dotpa * invd, 0.0f), 1.0f);
            float pa2 = fmaf(py, fmaf(py, 1.0f, -2.0f * ay), pa2_b);
            float d2 = fmaf(tt, fmaf(tt, denom, -2.0f * dotpa), pa2);
            float d = sqrtf(fmaxf(d2, 0.0f));
            float v = fmaxf(d - ws, 0.0f);
            minv[ry] = fminf(minv[ry], v);
        }
    }

    float sq = 0.f;
#pragma unroll
    for (int ry = 0; ry < ROWS_PER_BLK; ++ry) {
        float diff = pv[ry] - minv[ry];
        sq = fmaf(diff, diff, sq);
    }

#pragma unroll
    for (int off = 32; off > 0; off >>= 1) sq += __shfl_down(sq, off, 64);
    if ((t & 63) == 0) swsum[t >> 6] = sq;
    __syncthreads();
    if (t == 0) {
        float tot = swsum[0] + swsum[1] + swsum[2] + swsum[3] + swsum[4] + swsum[5];
        u64 pvv = ((u64)MAGICU << 32) | (u64)__float_as_uint(tot);
        __hip_atomic_store(&pflag[blk], pvv,
                           __ATOMIC_RELAXED, __HIP_MEMORY_SCOPE_AGENT);
    }

    // designated reducer: block 8 (co-residency guaranteed: 256 blocks/256 CUs)
    if (blk == 8) {
        __syncthreads();             // protect swsum reuse
        float v = 0.f;
        if (t < 256) {
            u64 pvv = __hip_atomic_load(&pflag[t], __ATOMIC_RELAXED,
                                        __HIP_MEMORY_SCOPE_AGENT);
            while ((u32)(pvv >> 32) != MAGICU) {
                __builtin_amdgcn_s_sleep(4);
                pvv = __hip_atomic_load(&pflag[t], __ATOMIC_RELAXED,
                                        __HIP_MEMORY_SCOPE_AGENT);
            }
            v = __uint_as_float((u32)pvv);
        }
#pragma unroll
        for (int off = 32; off > 0; off >>= 1) v += __shfl_down(v, off, 64);
        if ((t & 63) == 0) swsum[t >> 6] = v;
        __syncthreads();
        if (t == 0) {
            float tot = swsum[0] + swsum[1] + swsum[2] + swsum[3] + swsum[4] + swsum[5];
            out[0] = tot * (1.0f / (float)(BB * HWSZ));
        }
    }
}

extern "C" void kernel_launch(void* const* d_in, const int* in_sizes, int n_in,
                              void* d_out, int out_size, void* d_ws, size_t ws_size,
                              hipStream_t stream)
{
    const float* pred   = (const float*)d_in[0];   // (8,1,384,384)
    const float* nodes  = (const float*)d_in[1];   // (8,96,2)
    const float* widths = (const float*)d_in[2];   // (8,96)
    const float* fltr   = (const float*)d_in[3];   // (2,1,7,7)
    float* out = (float*)d_out;

    float* ws   = (float*)d_ws;
    float* g2   = ws;                               // 2*B*HW floats (float2 lanes)
    float* gw2  = g2 + (size_t)2 * BB * HWSZ;       // 2*B*HW
    float* segs = gw2 + (size_t)2 * BB * HWSZ;      // B * SEGPAD
    float* tail = segs + (size_t)BB * SEGPAD + 256; // pad away from segs
    u64* pflag = (u64*)tail;                        // 256 u64 (8B-aligned)
    // total ~19 MB << ws_size

    conv_fused<<<BB * CBANDS, 384, 0, stream>>>(pred, fltr,
                                                (float2*)g2, (float2*)gw2);
    snake_kernel<<<BB, 128, 0, stream>>>(nodes, widths, g2, gw2, segs);
    render_kernel<<<BB * NCHUNK, 384, 0, stream>>>(pred, segs, pflag, out);
}

// Round 6
// 118.799 us; speedup vs baseline: 1.0697x; 1.0063x over previous
//
#include <hip/hip_runtime.h>
#include <math.h>

#define BB   8
#define HH   384
#define WW   384
#define NN   96
#define HWSZ (HH * WW)
#define NSEG (NN - 1)
#define SEGF 12
#define SEGPAD 1152                  // NSEG*SEGF = 1140, padded
#define DMAXV 15.0f
#define ROWS_PER_BLK 12
#define NCHUNK (HH / ROWS_PER_BLK)   // 32
#define CROWS 12
#define CBANDS (HH / CROWS)          // 32
#define MAGICU 0x9E3779B9u

typedef unsigned long long u64;
typedef unsigned int u32;

// Relaxed agent-scope atomic store of a float pair (8B). Used ONLY for the
// tiny segs handoff (~37 KB) -- cheap at this volume, no cache maintenance.
__device__ inline void st_pair(float* p, float lo, float hi)
{
    u64 v = ((u64)__float_as_uint(hi) << 32) | (u64)__float_as_uint(lo);
    __hip_atomic_store((u64*)p, v, __ATOMIC_RELAXED, __HIP_MEMORY_SCOPE_AGENT);
}

__device__ inline float ld_f32_coh(const float* p)
{
    u32 v = __hip_atomic_load((u32*)p, __ATOMIC_RELAXED, __HIP_MEMORY_SCOPE_AGENT);
    return __uint_as_float(v);
}

#define WAIT_ALL() asm volatile("s_waitcnt vmcnt(0) lgkmcnt(0)" ::: "memory")

// raw barrier with LDS-only drain: gathers stay in flight across it
__device__ inline void lds_barrier()
{
    asm volatile("s_waitcnt lgkmcnt(0)" ::: "memory");
    __builtin_amdgcn_sched_barrier(0);
    __builtin_amdgcn_s_barrier();
    __builtin_amdgcn_sched_barrier(0);
}

// ---------------------------------------------------------------------------
// Separable 7x7 tap recovery (exact).
// ---------------------------------------------------------------------------
__device__ inline void load_taps(const float* __restrict__ fltr,
                                 float* __restrict__ sg, float* __restrict__ sdg)
{
    int tid = threadIdx.x;
    if (tid < 7) {
        float s = 0.f;
#pragma unroll
        for (int i = 0; i < 7; ++i) s += fabsf(fltr[i * 7 + tid]);
        sg[tid] = s;
    } else if (tid < 14) {
        int r = tid - 7;
        float s = 0.f;
#pragma unroll
        for (int j = 0; j < 7; ++j) s += fltr[r * 7 + j];
        sdg[r] = s;
    }
    __syncthreads();
}

// ---------------------------------------------------------------------------
// Kernel 1: fused separable conv (normal write-back stores; the dispatch
// boundary provides coherence to kernel 2).
// ---------------------------------------------------------------------------
__global__ __launch_bounds__(384) void conv_fused(
    const float* __restrict__ pred, const float* __restrict__ fltr,
    float2* __restrict__ g2, float2* __restrict__ gw2)
{
    __shared__ float sg[7], sdg[7];
    load_taps(fltr, sg, sdg);

    int blk = blockIdx.x;            // 256 blocks
    int b = blk & 7;                 // XCD co-location swizzle (perf only)
    int band = blk >> 3;
    int y0 = band * CROWS;
    int x = threadIdx.x;             // column 0..383
    const float* pb = pred + (size_t)b * HWSZ;
    bool xin = (x >= 3) && (x < WW - 3);

    float hg[7], hd[7], hga[7], hda[7];

#pragma unroll
    for (int q = 0; q < CROWS + 6; ++q) {
        float vg = 0.f, vd = 0.f, vga = 0.f, vda = 0.f;
        int r = y0 + q - 3;
        if (r >= 0 && r < HH) {
            const float* row = pb + r * WW;
            if (xin) {
#pragma unroll
                for (int k = 0; k < 7; ++k) {
                    float v  = row[x + k - 3];
                    float av = fabsf(v);
                    vg  = fmaf(v,  sg[k],  vg);
                    vd  = fmaf(v,  sdg[k], vd);
                    vga = fmaf(av, sg[k],  vga);
                    vda = fmaf(av, sdg[k], vda);
                }
            } else {
#pragma unroll
                for (int k = 0; k < 7; ++k) {
                    int ix = x + k - 3;
                    float v  = (ix >= 0 && ix < WW) ? row[ix] : 0.f;
                    float av = fabsf(v);
                    vg  = fmaf(v,  sg[k],  vg);
                    vd  = fmaf(v,  sdg[k], vd);
                    vga = fmaf(av, sg[k],  vga);
                    vda = fmaf(av, sdg[k], vda);
                }
            }
        }
        hg[q % 7] = vg; hd[q % 7] = vd; hga[q % 7] = vga; hda[q % 7] = vda;

        if (q >= 6) {
            int y = y0 + q - 6;
            float o0 = 0.f, o1 = 0.f, o2 = 0.f, o3 = 0.f;
#pragma unroll
            for (int j = 0; j < 7; ++j) {
                int s = (q - 6 + j) % 7;
                o0 = fmaf(hg[s],  sdg[j], o0);
                o1 = fmaf(hd[s],  sg[j],  o1);
                o2 = fmaf(hga[s], sdg[j], o2);
                o3 = fmaf(hda[s], sg[j],  o3);
            }
            size_t gi = (size_t)b * HWSZ + (size_t)y * WW + x;
            g2[gi]  = make_float2(o0 * 10.f, o1 * 10.f);
            gw2[gi] = make_float2(o2 * 10.f, o3 * 10.f);
        }
    }
}

// ---------------------------------------------------------------------------
// Bilinear sample on channel-interleaved 2-ch image (ref-identical math).
// ---------------------------------------------------------------------------
__device__ inline float2 bilin2i(const float2* __restrict__ img, float py, float px)
{
    float y = fminf(fmaxf(py, 0.0f), (float)(HH - 1));
    float x = fminf(fmaxf(px, 0.0f), (float)(WW - 1));
    int y0 = (int)floorf(y);
    int x0 = (int)floorf(x);
    int y1 = min(y0 + 1, HH - 1);
    bool xedge = (x0 + 1 > WW - 1);
    float wy = y - (float)y0;
    float wx = x - (float)x0;
    float4 r0 = *(const float4*)(img + y0 * WW + x0);
    float4 r1 = *(const float4*)(img + y1 * WW + x0);
    float2 v00 = make_float2(r0.x, r0.y);
    float2 v01 = xedge ? v00 : make_float2(r0.z, r0.w);
    float2 v10 = make_float2(r1.x, r1.y);
    float2 v11 = xedge ? v10 : make_float2(r1.z, r1.w);
    float w00 = (1.f - wy) * (1.f - wx);
    float w01 = (1.f - wy) * wx;
    float w10 = wy * (1.f - wx);
    float w11 = wy * wx;
    return make_float2(v00.x * w00 + v01.x * w01 + v10.x * w10 + v11.x * w11,
                       v00.y * w00 + v01.y * w01 + v10.y * w10 + v11.y * w11);
}

// write-through (coherent) seg record: 6 u64 relaxed atomic stores
__device__ inline void write_seg_wt(float* __restrict__ r,
                                    float py, float px, float qy, float qx, float wseg)
{
    float aby = qy - py, abx = qx - px;
    float denom = aby * aby + abx * abx + 1e-8f;
    float aab = py * aby + px * abx;
    float aa  = py * py + px * px;
    float reach = DMAXV + wseg;
    st_pair(r + 0,  py,  px);
    st_pair(r + 2,  aby, abx);
    st_pair(r + 4,  aab, denom);
    st_pair(r + 6,  1.0f / denom, aa);
    st_pair(r + 8,  wseg, fminf(py, qy) - reach);
    st_pair(r + 10, fmaxf(py, qy) + reach, 0.f);
}

// ---------------------------------------------------------------------------
// Kernel 2: MERGED snake + render (one dispatch boundary saved vs round 5).
//  - blocks 0..7: software-pipelined snake (2 waves x 48 active lanes, one
//    node per lane, LDS double-buffered exchange, raw lgkm-only barriers so
//    bilinear gathers stay in flight across steps), then render band 0.
//  - blocks 8..255: spin on segflag[b] (MAGIC, relaxed agent), then render.
//  - reduction: u64 MAGIC-tagged partials + designated reducer (block 8);
//    idempotent across graph replays. Deadlock-free: 256 blocks co-resident.
// All FP expression shapes identical to the verified kernel (absmax 0.0).
// ---------------------------------------------------------------------------
__global__ __launch_bounds__(384) void snake_render(
    const float* __restrict__ pred, const float* __restrict__ nodes,
    const float* __restrict__ widths,
    const float* __restrict__ g2f, const float* __restrict__ gw2f,
    float* __restrict__ segs, u64* __restrict__ pflag,
    u32* __restrict__ segflag, float* __restrict__ out)
{
    __shared__ float ss[NSEG * SEGF];
    __shared__ float2 posb[2][NN];
    __shared__ float  wbuf[NN];
    __shared__ int slo, shi;
    __shared__ float swsum[6];

    int blk = blockIdx.x;            // 256 blocks
    int b   = blk & 7;               // image (XCD co-location, perf-only)
    int band = blk >> 3;             // render chunk
    int t = threadIdx.x;

    // prefetch this thread's 12 pred values (hide under snake/spin)
    int y0r = band * ROWS_PER_BLK;
    const float* pb = pred + (size_t)b * HWSZ + (size_t)y0r * WW + t;
    float pv[ROWS_PER_BLK];
#pragma unroll
    for (int ry = 0; ry < ROWS_PER_BLK; ++ry) pv[ry] = pb[ry * WW];

    if (t == 0) { slo = NSEG; shi = -1; }

    // ================= phase B: snake (blocks 0..7) =================
    if (blk < 8) {
        const float2* gb  = (const float2*)g2f  + (size_t)b * HWSZ;
        const float2* gwb = (const float2*)gw2f + (size_t)b * HWSZ;
        int wv = t >> 6, ln = t & 63;
        int n  = wv * 48 + ln;            // node index (balanced 48/48)
        bool act = (wv < 2) && (ln < 48);
        bool n0f = (n == 0), nlf = (n == NN - 1);

        float py = 0.f, px = 0.f;
        float4 r0 = make_float4(0.f, 0.f, 0.f, 0.f), r1 = r0;
        float wy = 0.f, wx = 0.f;
        bool xedge = false;

        // prologue: load node, publish to LDS, issue gather for initial pos
        if (act) {
            float2 p0 = *(const float2*)(nodes + (size_t)(b * NN + n) * 2);
            py = p0.x; px = p0.y;
            posb[0][n] = p0;
            float yc = fminf(fmaxf(py, 0.0f), (float)(HH - 1));
            float xc = fminf(fmaxf(px, 0.0f), (float)(WW - 1));
            int y0i = (int)floorf(yc);
            int x0i = (int)floorf(xc);
            int y1i = min(y0i + 1, HH - 1);
            xedge = (x0i + 1 > WW - 1);
            wy = yc - (float)y0i;
            wx = xc - (float)x0i;
            r0 = *(const float4*)(gb + y0i * WW + x0i);
            r1 = *(const float4*)(gb + y1i * WW + x0i);
        }
        lds_barrier();                    // all 6 waves of the block

        // ---- 50 position steps, software-pipelined ----
        for (int s = 0; s < 50; ++s) {
            const float2* pcur = posb[s & 1];
            float2* pnxt = posb[(s & 1) ^ 1];
            if (act) {
                // LDS exchange + internal forces (overlaps in-flight gathers)
                float2 xm1 = pcur[max(n - 1, 0)];
                float2 xp1 = pcur[min(n + 1, NN - 1)];
                float2 xm2 = pcur[max(n - 2, 0)];
                float2 xp2 = pcur[min(n + 2, NN - 1)];

                float d2m_y = xm2.x - 2.f * xm1.x + py;
                float d2c_y = xm1.x - 2.f * py + xp1.x;
                float d2p_y = py - 2.f * xp1.x + xp2.x;
                float d2m_x = xm2.y - 2.f * xm1.y + px;
                float d2c_x = xm1.y - 2.f * px + xp1.y;
                float d2p_x = px - 2.f * xp1.y + xp2.y;
                d2m_y = n0f ? d2c_y : d2m_y;
                d2m_x = n0f ? d2c_x : d2m_x;
                d2p_y = nlf ? d2c_y : d2p_y;
                d2p_x = nlf ? d2c_x : d2p_x;
                float d4_y = d2m_y - 2.f * d2c_y + d2p_y;
                float d4_x = d2m_x - 2.f * d2c_x + d2p_x;

                // consume the gather issued LAST iteration (weights carried)
                float2 v00 = make_float2(r0.x, r0.y);
                float2 v01 = xedge ? v00 : make_float2(r0.z, r0.w);
                float2 v10 = make_float2(r1.x, r1.y);
                float2 v11 = xedge ? v10 : make_float2(r1.z, r1.w);
                float w00 = (1.f - wy) * (1.f - wx);
                float w01 = (1.f - wy) * wx;
                float w10 = wy * (1.f - wx);
                float w11 = wy * wx;
                float fy = v00.x * w00 + v01.x * w01 + v10.x * w10 + v11.x * w11;
                float fx = v00.y * w00 + v01.y * w01 + v10.y * w10 + v11.y * w11;

                py += 0.1f * (0.01f * d2c_y - 0.01f * d4_y + fy);
                px += 0.1f * (0.01f * d2c_x - 0.01f * d4_x + fx);

                // issue NEXT step's gather from the updated position
                float yc = fminf(fmaxf(py, 0.0f), (float)(HH - 1));
                float xc = fminf(fmaxf(px, 0.0f), (float)(WW - 1));
                int y0i = (int)floorf(yc);
                int x0i = (int)floorf(xc);
                int y1i = min(y0i + 1, HH - 1);
                xedge = (x0i + 1 > WW - 1);
                wy = yc - (float)y0i;
                wx = xc - (float)x0i;
                r0 = *(const float4*)(gb + y0i * WW + x0i);
                r1 = *(const float4*)(gb + y1i * WW + x0i);

                pnxt[n] = make_float2(py, px);
            }
            lds_barrier();             // LDS drain only; gathers stay in flight
        }
        // final positions: posb[0][*] and (py,px) registers

        // ---- tangent / normal / width loop ----
        float ny_ = 0.f, nx_ = 0.f, wn = 0.f;
        if (act) {
            float2 xm1 = posb[0][max(n - 1, 0)];
            float2 xp1 = posb[0][min(n + 1, NN - 1)];
            float ty, tx;
            if (n0f)      { ty = xp1.x - py;  tx = xp1.y - px; }
            else if (nlf) { ty = py - xm1.x;  tx = px - xm1.y; }
            else          { ty = 0.5f * (xp1.x - xm1.x); tx = 0.5f * (xp1.y - xm1.y); }

            float nn0 = -tx, nn1 = ty;
            float nrm = sqrtf(nn0 * nn0 + nn1 * nn1) + 1e-6f;
            ny_ = nn0 / nrm; nx_ = nn1 / nrm;

            wn = widths[b * NN + n];
            for (int s = 0; s < 10; ++s) {
                float2 gp = bilin2i(gwb, py + wn * ny_, px + wn * nx_);
                float2 gm = bilin2i(gwb, py - wn * ny_, px - wn * nx_);
                float fw = 0.5f * ((gp.x * ny_ + gp.y * nx_) - (gm.x * ny_ + gm.y * nx_));
                wn = fmaxf(wn + 0.1f * fw, 0.5f);
            }
            wbuf[n] = wn;
        }
        __syncthreads();               // wbuf ready

        // ---- seg write: tiny write-through handoff ----
        if (act && n < NSEG) {
            float2 q = posb[0][n + 1];
            float wq = wbuf[n + 1];
            write_seg_wt(segs + (size_t)b * SEGPAD + (size_t)n * SEGF,
                         py, px, q.x, q.y, 0.5f * (wn + wq));
        }
        WAIT_ALL();                    // this wave's seg stores committed
        __syncthreads();               // all waves committed
        if (t == 0)
            __hip_atomic_store(&segflag[b], MAGICU,
                               __ATOMIC_RELAXED, __HIP_MEMORY_SCOPE_AGENT);
    } else {
        if (t == 0) {
            while (__hip_atomic_load(&segflag[b],
                                     __ATOMIC_RELAXED, __HIP_MEMORY_SCOPE_AGENT) != MAGICU)
                __builtin_amdgcn_s_sleep(8);
            asm volatile("" ::: "memory");
        }
    }

    __syncthreads();                 // segs ready; slo/shi initialized

    // ================= phase C: render 12 rows + partial sum =================
    {
        int y0 = y0r;
        const float* sb = segs + (size_t)b * SEGPAD;
        for (int j = t; j < NSEG * SEGF; j += 384)
            ss[j] = ld_f32_coh(sb + j);      // one-shot coherent staging
        __syncthreads();

        float cy0 = (float)y0, cy1 = (float)(y0 + ROWS_PER_BLK - 1);
        if (t < NSEG) {
            float ylo = ss[t * SEGF + 9];
            float yhi = ss[t * SEGF + 10];
            if (yhi >= cy0 && ylo <= cy1) {
                atomicMin(&slo, t);
                atomicMax(&shi, t);
            }
        }
        __syncthreads();
        int lo = slo, hi = shi;

        float px = (float)t;
        float px2 = px * px;
        float minv[ROWS_PER_BLK];
#pragma unroll
        for (int r = 0; r < ROWS_PER_BLK; ++r) minv[r] = DMAXV;

        for (int si = lo; si <= hi; ++si) {
            const float* r = ss + si * SEGF;
            float ax = r[1], abx = r[3], ws = r[8];
            float bxe = ax + abx;
            float reach = DMAXV + ws + 0.01f;
            if (px < fminf(ax, bxe) - reach || px > fmaxf(ax, bxe) + reach) continue;

            float ay = r[0], aby = r[2];
            float aab = r[4], denom = r[5], invd = r[6], aa = r[7];
            float dotpa_b = fmaf(px, abx, -aab);
            float pa2_b   = fmaf(px, -2.0f * ax, px2 + aa);
#pragma unroll
            for (int ry = 0; ry < ROWS_PER_BLK; ++ry) {
                float py = (float)(y0 + ry);
                float dotpa = fmaf(py, aby, dotpa_b);
                float tt = fminf(fmaxf(dotpa * invd, 0.0f), 1.0f);
                float pa2 = fmaf(py, fmaf(py, 1.0f, -2.0f * ay), pa2_b);
                float d2 = fmaf(tt, fmaf(tt, denom, -2.0f * dotpa), pa2);
                float d = sqrtf(fmaxf(d2, 0.0f));
                float v = fmaxf(d - ws, 0.0f);
                minv[ry] = fminf(minv[ry], v);
            }
        }

        float sq = 0.f;
#pragma unroll
        for (int ry = 0; ry < ROWS_PER_BLK; ++ry) {
            float diff = pv[ry] - minv[ry];
            sq = fmaf(diff, diff, sq);
        }

#pragma unroll
        for (int off = 32; off > 0; off >>= 1) sq += __shfl_down(sq, off, 64);
        if ((t & 63) == 0) swsum[t >> 6] = sq;
        __syncthreads();
        if (t == 0) {
            float tot = swsum[0] + swsum[1] + swsum[2] + swsum[3] + swsum[4] + swsum[5];
            u64 pvv = ((u64)MAGICU << 32) | (u64)__float_as_uint(tot);
            __hip_atomic_store(&pflag[blk], pvv,
                               __ATOMIC_RELAXED, __HIP_MEMORY_SCOPE_AGENT);
        }
    }

    // ================= final reduce: designated block 8 =================
    if (blk == 8) {
        __syncthreads();             // protect swsum reuse
        float v = 0.f;
        if (t < 256) {
            u64 pvv = __hip_atomic_load(&pflag[t], __ATOMIC_RELAXED,
                                        __HIP_MEMORY_SCOPE_AGENT);
            while ((u32)(pvv >> 32) != MAGICU) {
                __builtin_amdgcn_s_sleep(4);
                pvv = __hip_atomic_load(&pflag[t], __ATOMIC_RELAXED,
                                        __HIP_MEMORY_SCOPE_AGENT);
            }
            v = __uint_as_float((u32)pvv);
        }
#pragma unroll
        for (int off = 32; off > 0; off >>= 1) v += __shfl_down(v, off, 64);
        if ((t & 63) == 0) swsum[t >> 6] = v;
        __syncthreads();
        if (t == 0) {
            float tot = swsum[0] + swsum[1] + swsum[2] + swsum[3] + swsum[4] + swsum[5];
            out[0] = tot * (1.0f / (float)(BB * HWSZ));
        }
    }
}

extern "C" void kernel_launch(void* const* d_in, const int* in_sizes, int n_in,
                              void* d_out, int out_size, void* d_ws, size_t ws_size,
                              hipStream_t stream)
{
    const float* pred   = (const float*)d_in[0];   // (8,1,384,384)
    const float* nodes  = (const float*)d_in[1];   // (8,96,2)
    const float* widths = (const float*)d_in[2];   // (8,96)
    const float* fltr   = (const float*)d_in[3];   // (2,1,7,7)
    float* out = (float*)d_out;

    float* ws   = (float*)d_ws;
    float* g2   = ws;                               // 2*B*HW floats (float2 lanes)
    float* gw2  = g2 + (size_t)2 * BB * HWSZ;       // 2*B*HW
    float* segs = gw2 + (size_t)2 * BB * HWSZ;      // B * SEGPAD
    float* tail = segs + (size_t)BB * SEGPAD + 256; // pad away from segs
    u64* pflag = (u64*)tail;                        // 256 u64 (8B-aligned)
    u32* segflag = (u32*)(pflag + 256);             // 8
    // total ~19 MB << ws_size

    conv_fused<<<BB * CBANDS, 384, 0, stream>>>(pred, fltr,
                                                (float2*)g2, (float2*)gw2);
    snake_render<<<BB * NCHUNK, 384, 0, stream>>>(pred, nodes, widths, g2, gw2,
                                                  segs, pflag, segflag, out);
}